// Round 1
// baseline (79.251 us; speedup 1.0000x reference)
//
#include <hip/hip_runtime.h>
#include <math.h>

#define NPTS 2048
#define NG 2
#define IMG_H 512
#define IMG_W 512
#define HW (IMG_H * IMG_W)
#define RENDER_SIZE (3 * HW)
// ln(255): sigma above this -> alpha < 1/255 -> contribution exactly zeroed
#define S_MAX 5.5412636f

__device__ __forceinline__ float sigmoidf_(float x) {
    return 1.0f / (1.0f + expf(-x));
}

// Kernel 1: zero render accumulator region of d_out; compute radii + visibility.
__global__ void init_kernel(const float* __restrict__ cov2d, float* __restrict__ out) {
    int i = blockIdx.x * blockDim.x + threadIdx.x;
    if (i < RENDER_SIZE) out[i] = 0.0f;
    if (i < NPTS) {
        float sxx = cov2d[i * 3 + 0] + 0.5f;
        float sxy = cov2d[i * 3 + 1];
        float syy = cov2d[i * 3 + 2] + 0.5f;
        // __f*_rn intrinsics: block FMA contraction so fp32 rounding matches the
        // numpy reference exactly through ceil() (radii must match an integer).
        float det = __fsub_rn(__fmul_rn(sxx, syy), __fmul_rn(sxy, sxy));
        bool valid = det > 1e-8f;
        float mid = __fmul_rn(0.5f, __fadd_rn(sxx, syy));
        float t = __fsub_rn(__fmul_rn(mid, mid), det);
        t = fmaxf(t, 0.1f);
        float lam = __fadd_rn(mid, sqrtf(t));
        float r = valid ? ceilf(__fmul_rn(3.0f, sqrtf(lam))) : 0.0f;
        out[RENDER_SIZE + i] = r;                              // radii (int value as float)
        out[RENDER_SIZE + NPTS + i] = (r > 0.0f) ? 1.0f : 0.0f; // visibility = radii > 0
    }
}

// Kernel 2: one block per point; splat its alpha>=1/255 bounding box with atomics.
__global__ __launch_bounds__(64) void splat_kernel(
    const float* __restrict__ xyz, const float* __restrict__ cov2d,
    const float* __restrict__ fdc, const float* __restrict__ opac,
    const float* __restrict__ gfreq, const float* __restrict__ gwts,
    float* __restrict__ out)
{
    int p = blockIdx.x;
    float sxx = cov2d[p * 3 + 0] + 0.5f;
    float sxy = cov2d[p * 3 + 1];
    float syy = cov2d[p * 3 + 2] + 0.5f;
    float det = sxx * syy - sxy * sxy;
    if (!(det > 1e-8f)) return;  // invalid -> alpha forced to 0 everywhere

    float inv = 1.0f / det;
    float ca = syy * inv;
    float cb = -sxy * inv;
    float cc = sxx * inv;

    float xn = xyz[p * 2 + 0];
    float yn = xyz[p * 2 + 1];
    float op = opac[p];

    float c0 = sigmoidf_(fdc[p * 3 + 0]);
    float c1 = sigmoidf_(fdc[p * 3 + 1]);
    float c2 = sigmoidf_(fdc[p * 3 + 2]);

    float fx0 = expf(gfreq[(p * NG + 0) * 2 + 0]);
    float fy0 = expf(gfreq[(p * NG + 0) * 2 + 1]);
    float fx1 = expf(gfreq[(p * NG + 1) * 2 + 0]);
    float fy1 = expf(gfreq[(p * NG + 1) * 2 + 1]);
    float w0 = sigmoidf_(gwts[p * NG + 0]);
    float w1 = sigmoidf_(gwts[p * NG + 1]);

    // Ellipse max extents: cc*det = sxx, ca*det = syy  =>  dx_max = sqrt(2*S*sxx)
    float dxm = sqrtf(2.0f * S_MAX * sxx) + 0.01f;
    float dym = sqrtf(2.0f * S_MAX * syy) + 0.01f;
    int x0 = max(0, (int)ceilf(xn - dxm - 0.5f));
    int x1 = min(IMG_W - 1, (int)floorf(xn + dxm - 0.5f));
    int y0 = max(0, (int)ceilf(yn - dym - 0.5f));
    int y1 = min(IMG_H - 1, (int)floorf(yn + dym - 0.5f));
    int bw = x1 - x0 + 1;
    int bh = y1 - y0 + 1;
    if (bw <= 0 || bh <= 0) return;
    int area = bw * bh;

    for (int idx = threadIdx.x; idx < area; idx += 64) {
        int ix = x0 + idx % bw;
        int iy = y0 + idx / bw;
        float dx = (ix + 0.5f) - xn;
        float dy = (iy + 0.5f) - yn;
        float sigma = 0.5f * (ca * dx * dx + cc * dy * dy) + cb * (dx * dy);
        float alpha = op * expf(-sigma);
        alpha = fminf(alpha, 0.999f);
        if (alpha < (1.0f / 255.0f)) continue;  // exact reference threshold
        float mod = 1.0f + w0 * cosf(fx0 * dx + fy0 * dy)
                         + w1 * cosf(fx1 * dx + fy1 * dy);
        float wgt = alpha * mod;
        int pix = iy * IMG_W + ix;
        atomicAdd(&out[pix],          wgt * c0);
        atomicAdd(&out[HW + pix],     wgt * c1);
        atomicAdd(&out[2 * HW + pix], wgt * c2);
    }
}

// Kernel 3: clamp render to [0,1] in place.
__global__ void clamp_kernel(float* __restrict__ out) {
    int i = blockIdx.x * blockDim.x + threadIdx.x;
    if (i < RENDER_SIZE) {
        float v = out[i];
        out[i] = fminf(fmaxf(v, 0.0f), 1.0f);
    }
}

extern "C" void kernel_launch(void* const* d_in, const int* in_sizes, int n_in,
                              void* d_out, int out_size, void* d_ws, size_t ws_size,
                              hipStream_t stream) {
    const float* xyz   = (const float*)d_in[0];
    const float* cov2d = (const float*)d_in[1];
    const float* fdc   = (const float*)d_in[2];
    const float* opac  = (const float*)d_in[3];
    const float* gfreq = (const float*)d_in[4];
    const float* gwts  = (const float*)d_in[5];
    // d_in[6] = background (unused by the render), d_in[7]=H, d_in[8]=W (constants)
    float* out = (float*)d_out;

    int blocks = (RENDER_SIZE + 255) / 256;
    init_kernel<<<blocks, 256, 0, stream>>>(cov2d, out);
    splat_kernel<<<NPTS, 64, 0, stream>>>(xyz, cov2d, fdc, opac, gfreq, gwts, out);
    clamp_kernel<<<blocks, 256, 0, stream>>>(out);
}